// Round 7
// baseline (229.735 us; speedup 1.0000x reference)
//
#include <hip/hip_runtime.h>
#include <stdint.h>
#include <stddef.h>

// ---------------------------------------------------------------------------
// BSplineKANLayer — R11: fused kernel, 1-barrier/tile double-buffered pipeline.
// R10 post-mortem: fusion killed the A16 round-trip (FETCH 58MB) but the
// per-tile schedule [stage+gen+write] -> bar -> 16 MFMA -> bar serialized the
// ~130cyc gen VALU with the ~77cyc MFMA burst: fused=163us, MfmaUtil 20.6,
// VALUBusy 35.5. (Conflicts 1.57M ~= 2.5us across 256 CUs — negligible.)
// R11: double-buffer As (4KB x2) and Bs (16KB x2); iteration t does
//   stageB(t+1 -> bufs^1) ; gen(t+1)->regs ; ds_write As^1 ; mfma(t, bufs)
//   ; one __syncthreads()
// Race-safety: iter t writes buf p^1; the barrier ending iter t-1 guarantees
// all reads of p^1 (= iter t-1's read buf) completed. gen x input is
// register-double-buffered (float4 per 4 tiles). Mapping/layouts identical
// to R10 (passed, absmax 0.0105).
// ---------------------------------------------------------------------------

typedef __attribute__((ext_vector_type(8))) _Float16 half8;  // 8 fp16 = 4 VGPRs
typedef __attribute__((ext_vector_type(4))) float f32x4;

#define IN_DIM   512
#define OUT_DIM  512
#define BATCH    16384
#define KCH      576     // uint4 chunks per row: 4608 fp16 = 576 * 16B

// RNE f32 -> fp16 pair packed in a uint (a low 16, b high 16)
__device__ __forceinline__ unsigned pk2(float a, float b) {
  _Float16 ha = (_Float16)a, hb = (_Float16)b;   // v_cvt_f16_f32 (RNE)
  unsigned short ua = __builtin_bit_cast(unsigned short, ha);
  unsigned short ub = __builtin_bit_cast(unsigned short, hb);
  return (unsigned)ua | ((unsigned)ub << 16);
}
__device__ __forceinline__ uint4 pk8(float4 a, float4 b) {
  uint4 r;
  r.x = pk2(a.x, a.y); r.y = pk2(a.z, a.w);
  r.z = pk2(b.x, b.y); r.w = pk2(b.z, b.w);
  return r;
}
__device__ __forceinline__ float4 silu4(float4 v) {
  float4 r;
  r.x = v.x / (1.f + __expf(-v.x));
  r.y = v.y / (1.f + __expf(-v.y));
  r.z = v.z / (1.f + __expf(-v.z));
  r.w = v.w / (1.f + __expf(-v.w));
  return r;
}

// Windowed cubic basis (uniform grid; matches reference's single-step-denom
// recursion exactly — verified R5..R10): 8 fp16 values for one (row,dim).
__device__ __forceinline__ uint4 basis8(float xv, float g0, float rh) {
  float u  = (xv - g0) * rh;
  float tf = floorf(u);
  float f  = u - tf;
  int   t  = (int)tf;
  bool valid = (u >= 0.f) && (u < 11.f);
  t = min(max(t, 0), 10);
  float f2 = f * f, f3 = f2 * f;
  float omf = 1.f - f;
  float v0 = omf * omf * omf;                          // j = t-3
  float v1 = fmaf(f2, fmaf(3.f, f, -6.f), 4.f);        // j = t-2
  float v2 = fmaf(f, fmaf(f, fmaf(-3.f, f, 3.f), 3.f), 1.f);  // j = t-1
  float v3 = f3;                                       // j = t
  uint64_t pack = ((uint64_t)pk2(v2, v3) << 32) | (uint64_t)pk2(v0, v1);
  pack = valid ? pack : 0ull;
  const int base = 48 - 16 * t;
  uint4 r;
  uint32_t* rp = (uint32_t*)&r;
  #pragma unroll
  for (int i = 0; i < 4; ++i) {
    int amt = base + 32 * i;                           // in [-112, 48]
    uint32_t lo = (amt >= 0 && amt < 64) ? (uint32_t)(pack >> amt) : 0u;
    uint32_t hi = (amt < 0 && amt > -64) ? (uint32_t)(pack << (-amt)) : 0u;
    rp[i] = lo | hi;
  }
  return r;
}

// ===========================================================================
// Kernel 0: per-dim constants (g0, 1/softplus(gsl)) — computed ONCE per dim.
// ===========================================================================
__global__ __launch_bounds__(256) void kan_consts(
    const float* __restrict__ gsl, const float* __restrict__ gstart,
    float2* __restrict__ cst)
{
  int d = blockIdx.x * 256 + threadIdx.x;
  if (d < IN_DIM) {
    float v  = gsl[d * 11];                            // all 11 identical
    float sp = fmaxf(v, 0.f) + log1pf(expf(-fabsf(v)));  // softplus = step h
    cst[d] = make_float2(gstart[d], 1.f / sp);
  }
}

// ===========================================================================
// Kernel 1: B16 prep (4.7 MB). Stored slot s = kt*4 + sc of row n holds the
// 8 fp16 weights for logical chunk c = (sc - rot) & 3, rot = (n>>1)&3:
//   kt < 128 (spline): dim = 128c + kt   -> coeffs[n][dim*8 .. +7]
//   kt >= 128 (silu) : j = 4(kt-128)+c   -> bwt[n][j*8 .. +7]
// ===========================================================================
__global__ __launch_bounds__(256) void kan_prepb(
    const float* __restrict__ coeffs,  // (512,4096)
    const float* __restrict__ bwt,     // (512,512)
    uint4* __restrict__ B16)           // [512][576]
{
  int id = blockIdx.x * 256 + threadIdx.x;             // < 512*576
  int n  = id / KCH;
  int s  = id - n * KCH;
  int kt = s >> 2, sc = s & 3;
  int rot = (n >> 1) & 3;
  int c   = (sc - rot) & 3;
  const float* src;
  if (kt < 128) {
    int dim = 128 * c + kt;
    src = coeffs + (size_t)n * 4096 + dim * 8;
  } else {
    int j = 4 * (kt - 128) + c;
    src = bwt + (size_t)n * 512 + j * 8;
  }
  float4 a = *(const float4*)src, b = *(const float4*)(src + 4);
  B16[id] = pk8(a, b);
}

// ===========================================================================
// Kernel 2: fused basis-gen + GEMM + epilogue, double-buffered 1-barrier/tile.
// grid = 512 (XCD-swizzled), 256 thr, LDS 44KB (2 blocks/CU).
// ===========================================================================
__device__ __forceinline__ void gload_lds16(const uint4* g, uint4* l) {
  __builtin_amdgcn_global_load_lds(
      (const __attribute__((address_space(1))) void*)g,
      (__attribute__((address_space(3))) void*)l, 16, 0, 0);
}

__global__ __launch_bounds__(256, 2) void kan_fused(
    const float* __restrict__ x,       // (16384,512)
    const uint4* __restrict__ B16,     // [512][576] packed fp16
    const float2* __restrict__ cst,    // (512,) per-dim (g0, 1/h)
    const float* __restrict__ rsc,     // (1,)
    float* __restrict__ out)           // (16384,512)
{
  __shared__ uint4  BsB[2][1024];      // [buf][256 n-rows][4 chunks] = 32 KB
  __shared__ uint4  AsB[2][256];       // [buf][64 rows][4 chunks]    =  8 KB
  __shared__ float2 Cs[512];           // per-dim consts              =  4 KB

  const int tid  = threadIdx.x;
  const int lane = tid & 63;
  const int wv   = tid >> 6;

  // XCD-chunked bijective swizzle (512 % 8 == 0).
  const int bid  = blockIdx.x;
  const int wg   = ((bid & 7) << 6) | (bid >> 3);
  const int row0 = (wg >> 1) << 6;     // m-panel * 64
  const int n0   = (wg & 1) << 8;      // n-half * 256

  const int q    = lane >> 4;          // k-chunk 0..3
  const int l15  = lane & 15;
  const int cq   = (q + ((l15 >> 1) & 3)) & 3;   // read-side un-rotation

  // A-gen mapping: thread (grow, gc) = (tid>>2, tid&3), 1 eval/k-tile
  const int grow  = tid >> 2;          // 0..63 local row
  const int gc    = tid & 3;           // logical chunk
  const int aslot = grow * 4 + ((gc + (grow >> 1)) & 3);  // rotated As slot
  const float* xrow = x + (size_t)(row0 + grow) * IN_DIM;

  // B staging: wave wv fills Bs slots [wv*64 + h*256, +64), h=0..3
  const uint4* gsb[4];
  #pragma unroll
  for (int h = 0; h < 4; ++h) {
    int s = wv * 64 + h * 256 + lane;
    gsb[h] = B16 + (size_t)(n0 + (s >> 2)) * KCH + (s & 3);
  }

  f32x4 acc[4][4];
  #pragma unroll
  for (int a = 0; a < 4; ++a)
    #pragma unroll
    for (int b = 0; b < 4; ++b)
      acc[a][b] = (f32x4){0.f, 0.f, 0.f, 0.f};

  auto stageB = [&](int buf, int kt) {
    #pragma unroll
    for (int h = 0; h < 4; ++h)
      gload_lds16(gsb[h] + kt * 4, &BsB[buf][wv * 64 + h * 256]);
  };
  auto do_mfma = [&](int buf) {
    half8 af[4], bg[4];
    #pragma unroll
    for (int tm = 0; tm < 4; ++tm)
      af[tm] = *(const half8*)&AsB[buf][(tm * 16 + l15) * 4 + cq];
    #pragma unroll
    for (int tn = 0; tn < 4; ++tn)
      bg[tn] = *(const half8*)&BsB[buf][(wv * 64 + tn * 16 + l15) * 4 + cq];
    #pragma unroll
    for (int tm = 0; tm < 4; ++tm)
      #pragma unroll
      for (int tn = 0; tn < 4; ++tn)
        acc[tm][tn] = __builtin_amdgcn_mfma_f32_16x16x32_f16(
            af[tm], bg[tn], acc[tm][tn], 0, 0, 0);
  };

  // ---- consts -> LDS; barrier so gen(0) can read any Cs entry ----
  for (int d = tid; d < IN_DIM; d += 256) Cs[d] = cst[d];
  __syncthreads();

  // ---- prologue: tile 0 into buf 0 ----
  float4 xv = *(const float4*)(xrow + 128 * gc);   // x for tiles 0..3
  {
    float2 c = Cs[128 * gc];
    AsB[0][aslot] = basis8(xv.x, c.x, c.y);
  }
  stageB(0, 0);
  __syncthreads();                                 // drains vmcnt(0) + ds

  // ---- main loop: compute tile t (buf p), prepare tile t+1 (buf p^1) ----
  for (int t = 0; t < 143; ++t) {
    const int p  = t & 1;
    const int tn_ = t + 1;

    stageB(p ^ 1, tn_);                            // issue 4 gloads early

    uint4 an;
    if (tn_ < 128) {                               // spline tile
      if ((tn_ & 3) == 0)
        xv = *(const float4*)(xrow + 128 * gc + tn_);
      const int ph = tn_ & 3;
      float xe = (ph == 0) ? xv.x : (ph == 1) ? xv.y : (ph == 2) ? xv.z : xv.w;
      float2 c = Cs[128 * gc + tn_];
      an = basis8(xe, c.x, c.y);
    } else {                                       // silu tile
      const float* xs = xrow + (4 * (tn_ - 128) + gc) * 8;
      float4 a_ = *(const float4*)xs, b_ = *(const float4*)(xs + 4);
      an = pk8(silu4(a_), silu4(b_));
    }
    AsB[p ^ 1][aslot] = an;

    do_mfma(p);
    __syncthreads();   // t+1 buffers ready; reads of buf p done block-wide
  }
  do_mfma(143 & 1);                                // final tile, buf 1

  // ===== epilogue: + res_scale*x, tanh, store. C/D row=(lane>>4)*4+reg ====
  const float rs = rsc[0];
  #pragma unroll
  for (int tm = 0; tm < 4; ++tm) {
    #pragma unroll
    for (int tn = 0; tn < 4; ++tn) {
      #pragma unroll
      for (int r = 0; r < 4; ++r) {
        int m = row0 + tm * 16 + q * 4 + r;
        int n = n0 + wv * 64 + tn * 16 + l15;
        float xg = x[(size_t)m * IN_DIM + n];
        float y  = acc[tm][tn][r] + rs * xg;
        float e  = __expf(-2.f * fabsf(y));
        float t  = copysignf((1.f - e) / (1.f + e), y);
        out[(size_t)m * OUT_DIM + n] = t;
      }
    }
  }
}

// ===========================================================================
// Fallback: verified R5 fused kernel (used only if workspace is too small).
// ===========================================================================
__device__ __forceinline__ int swz(int r, int c) {
  return r * 4 + ((c + (r >> 1)) & 3);
}

__global__ __launch_bounds__(256, 2) void kan_main(
    const float* __restrict__ x, const float* __restrict__ coeffs,
    const float* __restrict__ bwt, const float* __restrict__ gsl,
    const float* __restrict__ gstart, const float* __restrict__ rsc,
    float* __restrict__ out)
{
  __shared__ uint4 At[512];
  __shared__ uint4 Bt[512];
  __shared__ float2 Cs[512];

  const int tid  = threadIdx.x;
  const int lane = tid & 63;
  const int wv   = tid >> 6;
  const int row0 = blockIdx.y << 7;
  const int n0   = blockIdx.x << 7;

  const int q    = lane >> 4;
  const int l15  = lane & 15;
  const int wrow = (wv >> 1) << 6;
  const int wcol = (wv & 1) << 6;

  for (int d = tid; d < IN_DIM; d += 256) {
    float v  = gsl[d * 11];
    float sp = fmaxf(v, 0.f) + log1pf(expf(-fabsf(v)));
    Cs[d] = make_float2(gstart[d], 1.f / sp);
  }
  __syncthreads();

  f32x4 acc[4][4];
  #pragma unroll
  for (int a = 0; a < 4; ++a)
    #pragma unroll
    for (int b = 0; b < 4; ++b)
      acc[a][b] = (f32x4){0.f, 0.f, 0.f, 0.f};

  const int br0 = tid >> 2,        bc0 = tid & 3;
  const int br1 = (tid + 256) >> 2, bc1 = tid & 3;

  auto do_mfma = [&]() {
    half8 af[4], bg[4];
    #pragma unroll
    for (int tm = 0; tm < 4; ++tm) {
      int m = wrow + tm * 16 + l15;
      af[tm] = *(const half8*)&At[swz(m, q)];
    }
    #pragma unroll
    for (int tn = 0; tn < 4; ++tn) {
      int n = wcol + tn * 16 + l15;
      bg[tn] = *(const half8*)&Bt[swz(n, q)];
    }
    #pragma unroll
    for (int tm = 0; tm < 4; ++tm)
      #pragma unroll
      for (int tn = 0; tn < 4; ++tn)
        acc[tm][tn] = __builtin_amdgcn_mfma_f32_16x16x32_f16(
            af[tm], bg[tn], acc[tm][tn], 0, 0, 0);
  };

  const float* bp0 = coeffs + (size_t)(n0 + br0) * 4096 + 1024 * bc0;
  const float* bp1 = coeffs + (size_t)(n0 + br1) * 4096 + 1024 * bc1;
  const float* xp0 = x + (size_t)(row0 + lane) * IN_DIM + 128 * wv;
  const float* xp1 = xp0 + (size_t)64 * IN_DIM;

  for (int kt4 = 0; kt4 < 32; ++kt4) {
    float4 xa = *(const float4*)(xp0 + kt4 * 4);
    float4 xb = *(const float4*)(xp1 + kt4 * 4);
    float xr0[4] = {xa.x, xa.y, xa.z, xa.w};
    float xr1[4] = {xb.x, xb.y, xb.z, xb.w};
    #pragma unroll
    for (int j = 0; j < 4; ++j) {
      const int kt = kt4 * 4 + j;
      const float* s0 = bp0 + kt * 8;
      const float* s1 = bp1 + kt * 8;
      float4 b0a = *(const float4*)(s0), b0b = *(const float4*)(s0 + 4);
      float4 b1a = *(const float4*)(s1), b1b = *(const float4*)(s1 + 4);

      float2 c = Cs[128 * wv + kt];
      uint4 p0 = basis8(xr0[j], c.x, c.y);
      uint4 p1 = basis8(xr1[j], c.x, c.y);

      Bt[swz(br0, bc0)] = pk8(b0a, b0b);
      Bt[swz(br1, bc1)] = pk8(b1a, b1b);
      At[swz(lane, wv)]      = p0;
      At[swz(lane + 64, wv)] = p1;
      __syncthreads();
      do_mfma();
      __syncthreads();
    }
  }

  for (int kt = 0; kt < 16; ++kt) {
    const int k0 = kt * 32;
    const float* s0 = bwt + (size_t)(n0 + br0) * 512 + k0 + bc0 * 8;
    const float* s1 = bwt + (size_t)(n0 + br1) * 512 + k0 + bc1 * 8;
    float4 b0a = *(const float4*)(s0), b0b = *(const float4*)(s0 + 4);
    float4 b1a = *(const float4*)(s1), b1b = *(const float4*)(s1 + 4);

    uint4 p[2];
    #pragma unroll
    for (int rr = 0; rr < 2; ++rr) {
      int idx = tid + rr * 256;
      int r = idx >> 2, cch = idx & 3;
      const float* xs = x + (size_t)(row0 + r) * IN_DIM + k0 + cch * 8;
      float4 xc = *(const float4*)(xs), xd = *(const float4*)(xs + 4);
      float f[8] = {xc.x, xc.y, xc.z, xc.w, xd.x, xd.y, xd.z, xd.w};
      #pragma unroll
      for (int jj = 0; jj < 8; ++jj) f[jj] = f[jj] / (1.f + __expf(-f[jj]));
      p[rr].x = pk2(f[0], f[1]); p[rr].y = pk2(f[2], f[3]);
      p[rr].z = pk2(f[4], f[5]); p[rr].w = pk2(f[6], f[7]);
    }

    Bt[swz(br0, bc0)] = pk8(b0a, b0b);
    Bt[swz(br1, bc1)] = pk8(b1a, b1b);
    #pragma unroll
    for (int rr = 0; rr < 2; ++rr) {
      int idx = tid + rr * 256;
      At[swz(idx >> 2, idx & 3)] = p[rr];
    }
    __syncthreads();
    do_mfma();
    __syncthreads();
  }

  const float rs = rsc[0];
  #pragma unroll
  for (int tm = 0; tm < 4; ++tm) {
    #pragma unroll
    for (int tn = 0; tn < 4; ++tn) {
      #pragma unroll
      for (int r = 0; r < 4; ++r) {
        int m = row0 + wrow + tm * 16 + q * 4 + r;
        int n = n0 + wcol + tn * 16 + l15;
        float xv = x[(size_t)m * IN_DIM + n];
        float y  = acc[tm][tn][r] + rs * xv;
        float e  = __expf(-2.f * fabsf(y));
        float t  = copysignf((1.f - e) / (1.f + e), y);
        out[(size_t)m * OUT_DIM + n] = t;
      }
    }
  }
}

// ---------------------------------------------------------------------------
extern "C" void kernel_launch(void* const* d_in, const int* in_sizes, int n_in,
                              void* d_out, int out_size, void* d_ws, size_t ws_size,
                              hipStream_t stream) {
  const float* x      = (const float*)d_in[0];
  const float* coeffs = (const float*)d_in[1];
  const float* bwt    = (const float*)d_in[2];
  const float* gsl    = (const float*)d_in[3];
  const float* gstart = (const float*)d_in[4];
  const float* rsc    = (const float*)d_in[5];
  float* out = (float*)d_out;
  (void)in_sizes; (void)n_in; (void)out_size;

  const size_t needB = (size_t)OUT_DIM * KCH * 16;   // 4,718,592 B
  const size_t needC = (size_t)IN_DIM * 8;           //     4,096 B

  if (d_ws != nullptr && ws_size >= needB + needC) {
    uint4*  B16 = (uint4*)d_ws;
    float2* cst = (float2*)((char*)d_ws + needB);
    hipLaunchKernelGGL(kan_consts, dim3(2), dim3(256), 0, stream,
                       gsl, gstart, cst);
    hipLaunchKernelGGL(kan_prepb, dim3((OUT_DIM * KCH) / 256), dim3(256), 0,
                       stream, coeffs, bwt, B16);
    hipLaunchKernelGGL(kan_fused, dim3(512), dim3(256), 0, stream,
                       x, (const uint4*)B16, (const float2*)cst, rsc, out);
  } else {
    hipLaunchKernelGGL(kan_main, dim3(4, 128), dim3(256), 0, stream,
                       x, coeffs, bwt, gsl, gstart, rsc, out);
  }
}

// Round 10
// 212.290 us; speedup vs baseline: 1.0822x; 1.0822x over previous
//
#include <hip/hip_runtime.h>
#include <stdint.h>
#include <stddef.h>

// ---------------------------------------------------------------------------
// BSplineKANLayer — R12 (resubmitted unchanged; 2x infra timeout, never run).
// R11 post-mortem: 1-barrier dbuf = null (160us). Cycle accounting: measured
// 2667 cyc/tile/CU vs ~1200 serialized floor -> the stall is (a) gen at ILP=1
// (one ~25-op dependent basis8 chain per thread per tile, ~120cyc latency
// exposed) and (b) 144 full vmcnt/lgkm drains. R12 groups 4 k-tiles:
//   stage 16 gloads + gen 4 evals (ILP=4) -> bar -> 4x[ds_read + 16 MFMA]
//   -> bar
// 36 groups, 72 drains, MFMA:VALU per group ~2.3:1 (MFMA-dominant at last).
// Cs -> direct global reads (L1-resident 4KB); LDS = Bs 64KB + As 16KB =
// 80KB/block, 2 blocks/CU = exactly the 160KB pool (grid-limited anyway).
// Mapping/layouts identical to R10/R11 (both passed, absmax 0.0105).
// ---------------------------------------------------------------------------

typedef __attribute__((ext_vector_type(8))) _Float16 half8;  // 8 fp16 = 4 VGPRs
typedef __attribute__((ext_vector_type(4))) float f32x4;

#define IN_DIM   512
#define OUT_DIM  512
#define BATCH    16384
#define KCH      576     // uint4 chunks per row: 4608 fp16 = 576 * 16B

// RNE f32 -> fp16 pair packed in a uint (a low 16, b high 16)
__device__ __forceinline__ unsigned pk2(float a, float b) {
  _Float16 ha = (_Float16)a, hb = (_Float16)b;   // v_cvt_f16_f32 (RNE)
  unsigned short ua = __builtin_bit_cast(unsigned short, ha);
  unsigned short ub = __builtin_bit_cast(unsigned short, hb);
  return (unsigned)ua | ((unsigned)ub << 16);
}
__device__ __forceinline__ uint4 pk8(float4 a, float4 b) {
  uint4 r;
  r.x = pk2(a.x, a.y); r.y = pk2(a.z, a.w);
  r.z = pk2(b.x, b.y); r.w = pk2(b.z, b.w);
  return r;
}
__device__ __forceinline__ float4 silu4(float4 v) {
  float4 r;
  r.x = v.x / (1.f + __expf(-v.x));
  r.y = v.y / (1.f + __expf(-v.y));
  r.z = v.z / (1.f + __expf(-v.z));
  r.w = v.w / (1.f + __expf(-v.w));
  return r;
}

// Windowed cubic basis (uniform grid; matches reference's single-step-denom
// recursion exactly — verified R5..R11): 8 fp16 values for one (row,dim).
__device__ __forceinline__ uint4 basis8(float xv, float g0, float rh) {
  float u  = (xv - g0) * rh;
  float tf = floorf(u);
  float f  = u - tf;
  int   t  = (int)tf;
  bool valid = (u >= 0.f) && (u < 11.f);
  t = min(max(t, 0), 10);
  float f2 = f * f, f3 = f2 * f;
  float omf = 1.f - f;
  float v0 = omf * omf * omf;                          // j = t-3
  float v1 = fmaf(f2, fmaf(3.f, f, -6.f), 4.f);        // j = t-2
  float v2 = fmaf(f, fmaf(f, fmaf(-3.f, f, 3.f), 3.f), 1.f);  // j = t-1
  float v3 = f3;                                       // j = t
  uint64_t pack = ((uint64_t)pk2(v2, v3) << 32) | (uint64_t)pk2(v0, v1);
  pack = valid ? pack : 0ull;
  const int base = 48 - 16 * t;
  uint4 r;
  uint32_t* rp = (uint32_t*)&r;
  #pragma unroll
  for (int i = 0; i < 4; ++i) {
    int amt = base + 32 * i;                           // in [-112, 48]
    uint32_t lo = (amt >= 0 && amt < 64) ? (uint32_t)(pack >> amt) : 0u;
    uint32_t hi = (amt < 0 && amt > -64) ? (uint32_t)(pack << (-amt)) : 0u;
    rp[i] = lo | hi;
  }
  return r;
}

// ===========================================================================
// Kernel 0: per-dim constants (g0, 1/softplus(gsl)) — computed ONCE per dim.
// ===========================================================================
__global__ __launch_bounds__(256) void kan_consts(
    const float* __restrict__ gsl, const float* __restrict__ gstart,
    float2* __restrict__ cst)
{
  int d = blockIdx.x * 256 + threadIdx.x;
  if (d < IN_DIM) {
    float v  = gsl[d * 11];                            // all 11 identical
    float sp = fmaxf(v, 0.f) + log1pf(expf(-fabsf(v)));  // softplus = step h
    cst[d] = make_float2(gstart[d], 1.f / sp);
  }
}

// ===========================================================================
// Kernel 1: B16 prep (4.7 MB). Stored slot s = kt*4 + sc of row n holds the
// 8 fp16 weights for logical chunk c = (sc - rot) & 3, rot = (n>>1)&3:
//   kt < 128 (spline): dim = 128c + kt   -> coeffs[n][dim*8 .. +7]
//   kt >= 128 (silu) : j = 4(kt-128)+c   -> bwt[n][j*8 .. +7]
// ===========================================================================
__global__ __launch_bounds__(256) void kan_prepb(
    const float* __restrict__ coeffs,  // (512,4096)
    const float* __restrict__ bwt,     // (512,512)
    uint4* __restrict__ B16)           // [512][576]
{
  int id = blockIdx.x * 256 + threadIdx.x;             // < 512*576
  int n  = id / KCH;
  int s  = id - n * KCH;
  int kt = s >> 2, sc = s & 3;
  int rot = (n >> 1) & 3;
  int c   = (sc - rot) & 3;
  const float* src;
  if (kt < 128) {
    int dim = 128 * c + kt;
    src = coeffs + (size_t)n * 4096 + dim * 8;
  } else {
    int j = 4 * (kt - 128) + c;
    src = bwt + (size_t)n * 512 + j * 8;
  }
  float4 a = *(const float4*)src, b = *(const float4*)(src + 4);
  B16[id] = pk8(a, b);
}

// ===========================================================================
// Kernel 2: fused basis-gen + GEMM + epilogue, G=4 K-grouping.
// grid = 512 (XCD-swizzled), 256 thr, LDS 80KB (2 blocks/CU = full pool).
// ===========================================================================
__device__ __forceinline__ void gload_lds16(const uint4* g, uint4* l) {
  __builtin_amdgcn_global_load_lds(
      (const __attribute__((address_space(1))) void*)g,
      (__attribute__((address_space(3))) void*)l, 16, 0, 0);
}

__global__ __launch_bounds__(256, 2) void kan_fused(
    const float* __restrict__ x,       // (16384,512)
    const uint4* __restrict__ B16,     // [512][576] packed fp16
    const float2* __restrict__ cst,    // (512,) per-dim (g0, 1/h)
    const float* __restrict__ rsc,     // (1,)
    float* __restrict__ out)           // (16384,512)
{
  __shared__ uint4 Bs[4][1024];        // [j][256 n-rows][4 chunks] = 64 KB
  __shared__ uint4 As[4][256];         // [j][64 rows][4 chunks]    = 16 KB

  const int tid  = threadIdx.x;
  const int lane = tid & 63;
  const int wv   = tid >> 6;

  // XCD-chunked bijective swizzle (512 % 8 == 0).
  const int bid  = blockIdx.x;
  const int wg   = ((bid & 7) << 6) | (bid >> 3);
  const int row0 = (wg >> 1) << 6;     // m-panel * 64
  const int n0   = (wg & 1) << 8;      // n-half * 256

  const int q    = lane >> 4;          // k-chunk 0..3
  const int l15  = lane & 15;
  const int cq   = (q + ((l15 >> 1) & 3)) & 3;   // read-side un-rotation

  // A-gen mapping: thread (grow, gc) = (tid>>2, tid&3), 1 eval per k-tile
  const int grow  = tid >> 2;          // 0..63 local row
  const int gc    = tid & 3;           // logical chunk
  const int aslot = grow * 4 + ((gc + (grow >> 1)) & 3);  // rotated As slot
  const float* xrow = x + (size_t)(row0 + grow) * IN_DIM;

  // B staging: wave wv fills Bs slots [wv*64 + h*256, +64), h=0..3
  const uint4* gsb[4];
  #pragma unroll
  for (int h = 0; h < 4; ++h) {
    int s = wv * 64 + h * 256 + lane;
    gsb[h] = B16 + (size_t)(n0 + (s >> 2)) * KCH + (s & 3);
  }

  f32x4 acc[4][4];
  #pragma unroll
  for (int a = 0; a < 4; ++a)
    #pragma unroll
    for (int b = 0; b < 4; ++b)
      acc[a][b] = (f32x4){0.f, 0.f, 0.f, 0.f};

  // ==== 36 groups of 4 k-tiles: 32 spline + 4 silu ====
  for (int g = 0; g < 36; ++g) {
    // ---- stage 4 B-tiles (16 gloads) ----
    #pragma unroll
    for (int j = 0; j < 4; ++j) {
      const int kt = g * 4 + j;
      #pragma unroll
      for (int h = 0; h < 4; ++h)
        gload_lds16(gsb[h] + kt * 4, &Bs[j][wv * 64 + h * 256]);
    }
    // ---- gen 4 A-tiles (4 independent evals, ILP=4) ----
    if (g < 32) {
      const int d0 = 128 * gc + g * 4;               // dims d0..d0+3 (16B-al.)
      float4 xv  = *(const float4*)(xrow + d0);
      float4 c01 = *(const float4*)(cst + d0);       // (g0,rh) dims d0,d0+1
      float4 c23 = *(const float4*)(cst + d0 + 2);   // (g0,rh) dims d0+2,+3
      As[0][aslot] = basis8(xv.x, c01.x, c01.y);
      As[1][aslot] = basis8(xv.y, c01.z, c01.w);
      As[2][aslot] = basis8(xv.z, c23.x, c23.y);
      As[3][aslot] = basis8(xv.w, c23.z, c23.w);
    } else {
      #pragma unroll
      for (int j = 0; j < 4; ++j) {
        const int kp = (g - 32) * 4 + j;             // 0..15
        const float* xs = xrow + (4 * kp + gc) * 8;
        float4 a_ = *(const float4*)xs, b_ = *(const float4*)(xs + 4);
        As[j][aslot] = pk8(silu4(a_), silu4(b_));
      }
    }
    __syncthreads();                                 // drains vm + lgkm

    // ---- compute 4 tiles: 64 MFMA ----
    #pragma unroll
    for (int j = 0; j < 4; ++j) {
      half8 af[4], bg[4];
      #pragma unroll
      for (int tm = 0; tm < 4; ++tm)
        af[tm] = *(const half8*)&As[j][(tm * 16 + l15) * 4 + cq];
      #pragma unroll
      for (int tn = 0; tn < 4; ++tn)
        bg[tn] = *(const half8*)&Bs[j][(wv * 64 + tn * 16 + l15) * 4 + cq];
      #pragma unroll
      for (int tm = 0; tm < 4; ++tm)
        #pragma unroll
        for (int tn = 0; tn < 4; ++tn)
          acc[tm][tn] = __builtin_amdgcn_mfma_f32_16x16x32_f16(
              af[tm], bg[tn], acc[tm][tn], 0, 0, 0);
    }
    __syncthreads();                                 // protect As/Bs reuse
  }

  // ===== epilogue: + res_scale*x, tanh, store. C/D row=(lane>>4)*4+reg ====
  const float rs = rsc[0];
  #pragma unroll
  for (int tm = 0; tm < 4; ++tm) {
    #pragma unroll
    for (int tn = 0; tn < 4; ++tn) {
      #pragma unroll
      for (int r = 0; r < 4; ++r) {
        int m = row0 + tm * 16 + q * 4 + r;
        int n = n0 + wv * 64 + tn * 16 + l15;
        float xg = x[(size_t)m * IN_DIM + n];
        float y  = acc[tm][tn][r] + rs * xg;
        float e  = __expf(-2.f * fabsf(y));
        float t  = copysignf((1.f - e) / (1.f + e), y);
        out[(size_t)m * OUT_DIM + n] = t;
      }
    }
  }
}

// ===========================================================================
// Fallback: verified R5 fused kernel (used only if workspace is too small).
// ===========================================================================
__device__ __forceinline__ int swz(int r, int c) {
  return r * 4 + ((c + (r >> 1)) & 3);
}

__global__ __launch_bounds__(256, 2) void kan_main(
    const float* __restrict__ x, const float* __restrict__ coeffs,
    const float* __restrict__ bwt, const float* __restrict__ gsl,
    const float* __restrict__ gstart, const float* __restrict__ rsc,
    float* __restrict__ out)
{
  __shared__ uint4 At[512];
  __shared__ uint4 Bt[512];
  __shared__ float2 Cs[512];

  const int tid  = threadIdx.x;
  const int lane = tid & 63;
  const int wv   = tid >> 6;
  const int row0 = blockIdx.y << 7;
  const int n0   = blockIdx.x << 7;

  const int q    = lane >> 4;
  const int l15  = lane & 15;
  const int wrow = (wv >> 1) << 6;
  const int wcol = (wv & 1) << 6;

  for (int d = tid; d < IN_DIM; d += 256) {
    float v  = gsl[d * 11];
    float sp = fmaxf(v, 0.f) + log1pf(expf(-fabsf(v)));
    Cs[d] = make_float2(gstart[d], 1.f / sp);
  }
  __syncthreads();

  f32x4 acc[4][4];
  #pragma unroll
  for (int a = 0; a < 4; ++a)
    #pragma unroll
    for (int b = 0; b < 4; ++b)
      acc[a][b] = (f32x4){0.f, 0.f, 0.f, 0.f};

  const int br0 = tid >> 2,        bc0 = tid & 3;
  const int br1 = (tid + 256) >> 2, bc1 = tid & 3;

  auto do_mfma = [&]() {
    half8 af[4], bg[4];
    #pragma unroll
    for (int tm = 0; tm < 4; ++tm) {
      int m = wrow + tm * 16 + l15;
      af[tm] = *(const half8*)&At[swz(m, q)];
    }
    #pragma unroll
    for (int tn = 0; tn < 4; ++tn) {
      int n = wcol + tn * 16 + l15;
      bg[tn] = *(const half8*)&Bt[swz(n, q)];
    }
    #pragma unroll
    for (int tm = 0; tm < 4; ++tm)
      #pragma unroll
      for (int tn = 0; tn < 4; ++tn)
        acc[tm][tn] = __builtin_amdgcn_mfma_f32_16x16x32_f16(
            af[tm], bg[tn], acc[tm][tn], 0, 0, 0);
  };

  const float* bp0 = coeffs + (size_t)(n0 + br0) * 4096 + 1024 * bc0;
  const float* bp1 = coeffs + (size_t)(n0 + br1) * 4096 + 1024 * bc1;
  const float* xp0 = x + (size_t)(row0 + lane) * IN_DIM + 128 * wv;
  const float* xp1 = xp0 + (size_t)64 * IN_DIM;

  for (int kt4 = 0; kt4 < 32; ++kt4) {
    float4 xa = *(const float4*)(xp0 + kt4 * 4);
    float4 xb = *(const float4*)(xp1 + kt4 * 4);
    float xr0[4] = {xa.x, xa.y, xa.z, xa.w};
    float xr1[4] = {xb.x, xb.y, xb.z, xb.w};
    #pragma unroll
    for (int j = 0; j < 4; ++j) {
      const int kt = kt4 * 4 + j;
      const float* s0 = bp0 + kt * 8;
      const float* s1 = bp1 + kt * 8;
      float4 b0a = *(const float4*)(s0), b0b = *(const float4*)(s0 + 4);
      float4 b1a = *(const float4*)(s1), b1b = *(const float4*)(s1 + 4);

      float2 c = Cs[128 * wv + kt];
      uint4 p0 = basis8(xr0[j], c.x, c.y);
      uint4 p1 = basis8(xr1[j], c.x, c.y);

      Bt[swz(br0, bc0)] = pk8(b0a, b0b);
      Bt[swz(br1, bc1)] = pk8(b1a, b1b);
      At[swz(lane, wv)]      = p0;
      At[swz(lane + 64, wv)] = p1;
      __syncthreads();
      do_mfma();
      __syncthreads();
    }
  }

  for (int kt = 0; kt < 16; ++kt) {
    const int k0 = kt * 32;
    const float* s0 = bwt + (size_t)(n0 + br0) * 512 + k0 + bc0 * 8;
    const float* s1 = bwt + (size_t)(n0 + br1) * 512 + k0 + bc1 * 8;
    float4 b0a = *(const float4*)(s0), b0b = *(const float4*)(s0 + 4);
    float4 b1a = *(const float4*)(s1), b1b = *(const float4*)(s1 + 4);

    uint4 p[2];
    #pragma unroll
    for (int rr = 0; rr < 2; ++rr) {
      int idx = tid + rr * 256;
      int r = idx >> 2, cch = idx & 3;
      const float* xs = x + (size_t)(row0 + r) * IN_DIM + k0 + cch * 8;
      float4 xc = *(const float4*)(xs), xd = *(const float4*)(xs + 4);
      float f[8] = {xc.x, xc.y, xc.z, xc.w, xd.x, xd.y, xd.z, xd.w};
      #pragma unroll
      for (int jj = 0; jj < 8; ++jj) f[jj] = f[jj] / (1.f + __expf(-f[jj]));
      p[rr].x = pk2(f[0], f[1]); p[rr].y = pk2(f[2], f[3]);
      p[rr].z = pk2(f[4], f[5]); p[rr].w = pk2(f[6], f[7]);
    }

    Bt[swz(br0, bc0)] = pk8(b0a, b0b);
    Bt[swz(br1, bc1)] = pk8(b1a, b1b);
    #pragma unroll
    for (int rr = 0; rr < 2; ++rr) {
      int idx = tid + rr * 256;
      At[swz(idx >> 2, idx & 3)] = p[rr];
    }
    __syncthreads();
    do_mfma();
    __syncthreads();
  }

  const float rs = rsc[0];
  #pragma unroll
  for (int tm = 0; tm < 4; ++tm) {
    #pragma unroll
    for (int tn = 0; tn < 4; ++tn) {
      #pragma unroll
      for (int r = 0; r < 4; ++r) {
        int m = row0 + wrow + tm * 16 + q * 4 + r;
        int n = n0 + wcol + tn * 16 + l15;
        float xv = x[(size_t)m * IN_DIM + n];
        float y  = acc[tm][tn][r] + rs * xv;
        float e  = __expf(-2.f * fabsf(y));
        float t  = copysignf((1.f - e) / (1.f + e), y);
        out[(size_t)m * OUT_DIM + n] = t;
      }
    }
  }
}

// ---------------------------------------------------------------------------
extern "C" void kernel_launch(void* const* d_in, const int* in_sizes, int n_in,
                              void* d_out, int out_size, void* d_ws, size_t ws_size,
                              hipStream_t stream) {
  const float* x      = (const float*)d_in[0];
  const float* coeffs = (const float*)d_in[1];
  const float* bwt    = (const float*)d_in[2];
  const float* gsl    = (const float*)d_in[3];
  const float* gstart = (const float*)d_in[4];
  const float* rsc    = (const float*)d_in[5];
  float* out = (float*)d_out;
  (void)in_sizes; (void)n_in; (void)out_size;

  const size_t needB = (size_t)OUT_DIM * KCH * 16;   // 4,718,592 B
  const size_t needC = (size_t)IN_DIM * 8;           //     4,096 B

  if (d_ws != nullptr && ws_size >= needB + needC) {
    uint4*  B16 = (uint4*)d_ws;
    float2* cst = (float2*)((char*)d_ws + needB);
    hipLaunchKernelGGL(kan_consts, dim3(2), dim3(256), 0, stream,
                       gsl, gstart, cst);
    hipLaunchKernelGGL(kan_prepb, dim3((OUT_DIM * KCH) / 256), dim3(256), 0,
                       stream, coeffs, bwt, B16);
    hipLaunchKernelGGL(kan_fused, dim3(512), dim3(256), 0, stream,
                       x, (const uint4*)B16, (const float2*)cst, rsc, out);
  } else {
    hipLaunchKernelGGL(kan_main, dim3(4, 128), dim3(256), 0, stream,
                       x, coeffs, bwt, gsl, gstart, rsc, out);
  }
}